// Round 2
// baseline (325.419 us; speedup 1.0000x reference)
//
#include <hip/hip_runtime.h>

// B=128, N=256, D=O=512. R = B*N = 32768 rows.
// Pipeline (3 kernels):
//   prep_w:  W -> W^T f16
//   mega:    per 64-row slab: LN1(Obs)->sX, then {GEMM1+tanh -> h1(regs) ->
//            LN2 -> sX, GEMM2+tanh+h1 -> LN3 -> sX, GEMM3 -> logits fp32}.
//            A1/A2/A3/h1 never touch HBM.
//   softmax: masked softmax over N
// mega K-loop: minimum-2-phase schedule (catalog T3 recipe): issue next-panel
// global_load_lds, ds_read current panel, MFMA, ONE __syncthreads per step
// (vmcnt(0)+lgkmcnt(0)+barrier). No inline-asm waits, no raw barriers --
// the counted-vmcnt variant from last round is the prime crash suspect.

#define NN 256

typedef _Float16 f16;
typedef __attribute__((ext_vector_type(4))) _Float16 f16x4;
typedef __attribute__((ext_vector_type(8))) _Float16 f16x8;
typedef __attribute__((ext_vector_type(4))) float f32x4;

#define XS    520   // sX row stride (f16): 1040 B, 16B-aligned, rows spread banks
#define EPS32 516   // f32 logits epilogue stride

__device__ __forceinline__ float fast_tanh(float x) {
  float e = __expf(2.f * x);
  return 1.f - 2.f * __builtin_amdgcn_rcpf(e + 1.f);
}
__device__ __forceinline__ void async_copy16(const void* g, void* l) {
  __builtin_amdgcn_global_load_lds(
      (const __attribute__((address_space(1))) unsigned int*)g,
      (__attribute__((address_space(3))) unsigned int*)l, 16, 0, 0);
}

// ---- Transpose + f16-cast weights: W[d][o] fp32 -> WT[o][d] f16 (3 stages) ----
__global__ void prep_w_kernel(const float* __restrict__ W1, const float* __restrict__ W2,
                              const float* __restrict__ W3, f16* __restrict__ WT) {
  int idx = blockIdx.x * 256 + threadIdx.x;
  int s   = idx >> 18;
  int rem = idx & 0x3FFFF;
  int o   = rem >> 9;
  int d   = rem & 511;
  const float* W = (s == 0) ? W1 : (s == 1) ? W2 : W3;
  WT[idx] = (f16)W[d * 512 + o];
}

// ---- stage one [512][32] f16 B-panel (chunk c of K) via global_load_lds ----
// Each wave stages rows wv*64..wv*64+63 and later reads ONLY those rows, so
// per-wave vmcnt drain at __syncthreads is sufficient for B correctness.
__device__ __forceinline__ void stage_b(const f16* __restrict__ Bg, f16* __restrict__ dst,
                                        int wv, int lane, int c) {
  #pragma unroll
  for (int q = 0; q < 4; ++q) {
    int r0 = wv * 64 + q * 16;
    const f16* gb = Bg + (((size_t)(r0 + (lane >> 2))) << 9) + c * 32 + (lane & 3) * 8;
    async_copy16(gb, dst + r0 * 32);
  }
}

// ---- Mega kernel: LN1 + 3 GEMMs + 2 LNs + tanh + residual, one 64-row slab ----
__global__ __launch_bounds__(512, 2) void mega_kernel(
    const float* __restrict__ Obs,
    const float* __restrict__ g1, const float* __restrict__ b1,
    const f16* __restrict__ WT,
    const float* __restrict__ g2, const float* __restrict__ b2,
    const float* __restrict__ g3, const float* __restrict__ b3,
    float* __restrict__ outF) {
  __shared__ __align__(16) char smem[136704];
  f16* sX  = (f16*)smem;                   // [64][XS] activations (A operand)
  f16* sB0 = (f16*)(smem + 66560);         // [512][32] B panel, even chunks
  f16* sB1 = (f16*)(smem + 99328);         // [512][32] B panel, odd chunks
  float2* sPart = (float2*)(smem + 132096);  // [512] per-wave LN partials
  float2* sStat = (float2*)(smem + 136192);  // [64] (mean, inv) per row

  int t = threadIdx.x, lane = t & 63, wv = t >> 6;
  int row16 = lane & 15, quad = lane >> 4;
  int rBase = blockIdx.x * 64;

  // prefetch GEMM1 chunk 0 (flies under the LN1 prologue)
  stage_b(WT, sB0, wv, lane, 0);

  // ---- LN1 prologue: each wave normalizes its 8 rows of Obs into sX ----
  {
    float4 w0 = *(const float4*)(g1 + lane * 4);
    float4 u0 = *(const float4*)(b1 + lane * 4);
    float4 w1 = *(const float4*)(g1 + 256 + lane * 4);
    float4 u1 = *(const float4*)(b1 + 256 + lane * 4);
    #pragma unroll
    for (int p = 0; p < 8; ++p) {
      int row = wv * 8 + p;
      const float* x = Obs + (((size_t)(rBase + row)) << 9);
      float4 v0 = *(const float4*)(x + lane * 4);
      float4 v1 = *(const float4*)(x + 256 + lane * 4);
      float s = v0.x + v0.y + v0.z + v0.w + v1.x + v1.y + v1.z + v1.w;
      float q = v0.x*v0.x + v0.y*v0.y + v0.z*v0.z + v0.w*v0.w
              + v1.x*v1.x + v1.y*v1.y + v1.z*v1.z + v1.w*v1.w;
      #pragma unroll
      for (int off = 1; off < 64; off <<= 1) {
        s += __shfl_xor(s, off, 64);
        q += __shfl_xor(q, off, 64);
      }
      float mean = s * (1.f / 512.f);
      float var  = q * (1.f / 512.f) - mean * mean;
      float inv  = 1.f / sqrtf(var + 1e-5f);
      f16x4 o0, o1;
      o0[0] = (f16)((v0.x - mean) * inv * w0.x + u0.x);
      o0[1] = (f16)((v0.y - mean) * inv * w0.y + u0.y);
      o0[2] = (f16)((v0.z - mean) * inv * w0.z + u0.z);
      o0[3] = (f16)((v0.w - mean) * inv * w0.w + u0.w);
      o1[0] = (f16)((v1.x - mean) * inv * w1.x + u1.x);
      o1[1] = (f16)((v1.y - mean) * inv * w1.y + u1.y);
      o1[2] = (f16)((v1.z - mean) * inv * w1.z + u1.z);
      o1[3] = (f16)((v1.w - mean) * inv * w1.w + u1.w);
      *(f16x4*)&sX[row * XS + lane * 4] = o0;
      *(f16x4*)&sX[row * XS + 256 + lane * 4] = o1;
    }
  }

  f32x4 acc[4][4];
  f16x4 h1s[4][4];   // residual tanh(A1@W1) stays in registers across GEMM2

  __syncthreads();   // sX ready (all waves); sB0 chunk 0 landed (vmcnt(0))

  for (int g = 0; g < 3; ++g) {
    const f16* Bg = WT + ((size_t)g << 18);

    #pragma unroll
    for (int mi = 0; mi < 4; ++mi)
      #pragma unroll
      for (int ni = 0; ni < 4; ++ni)
        acc[mi][ni] = (f32x4){0.f, 0.f, 0.f, 0.f};

    for (int c = 0; c < 16; ++c) {
      // issue next chunk into the other buffer; it overlaps this step's MFMAs
      // and is drained by this step's __syncthreads (vmcnt(0)).
      if (c < 15) stage_b(Bg, (c & 1) ? sB0 : sB1, wv, lane, c + 1);

      const f16* bb = (c & 1) ? sB1 : sB0;
      f16x8 af[4], bf[4];
      #pragma unroll
      for (int i = 0; i < 4; ++i) {
        int ar = i * 16 + row16;
        af[i] = *(const f16x8*)&sX[ar * XS + c * 32 + quad * 8];
        int br = wv * 64 + i * 16 + row16;
        bf[i] = *(const f16x8*)&bb[br * 32 + quad * 8];
      }
      #pragma unroll
      for (int mi = 0; mi < 4; ++mi)
        #pragma unroll
        for (int ni = 0; ni < 4; ++ni)
          acc[mi][ni] = __builtin_amdgcn_mfma_f32_16x16x32_f16(af[mi], bf[ni], acc[mi][ni], 0, 0, 0);

      __syncthreads();
    }

    if (g == 2) {
      // logits epilogue: fp32 assembled full-line writes (overlay sX region)
      float* sE = (float*)smem;
      #pragma unroll
      for (int half = 0; half < 2; ++half) {
        #pragma unroll
        for (int mi = 0; mi < 2; ++mi) {
          int rt = half * 2 + mi;
          #pragma unroll
          for (int ni = 0; ni < 4; ++ni) {
            int col = wv * 64 + ni * 16 + row16;
            #pragma unroll
            for (int rg = 0; rg < 4; ++rg)
              sE[(mi * 16 + quad * 4 + rg) * EPS32 + col] = acc[rt][ni][rg];
          }
        }
        __syncthreads();
        #pragma unroll
        for (int i = 0; i < 8; ++i) {
          int gi = t + i * 512;
          int row = gi >> 7, cg = (gi & 127) * 4;
          f32x4 v = *(const f32x4*)&sE[row * EPS32 + cg];
          *(f32x4*)&outF[(((size_t)(rBase + half * 32 + row)) << 9) + cg] = v;
        }
        __syncthreads();
      }
    } else {
      // tanh
      #pragma unroll
      for (int mi = 0; mi < 4; ++mi)
        #pragma unroll
        for (int ni = 0; ni < 4; ++ni)
          #pragma unroll
          for (int rg = 0; rg < 4; ++rg)
            acc[mi][ni][rg] = fast_tanh(acc[mi][ni][rg]);

      if (g == 0) {
        // stash h1 in registers (same (row,col) mapping as GEMM2's acc)
        #pragma unroll
        for (int mi = 0; mi < 4; ++mi)
          #pragma unroll
          for (int ni = 0; ni < 4; ++ni) {
            f16x4 h;
            #pragma unroll
            for (int rg = 0; rg < 4; ++rg) h[rg] = (f16)acc[mi][ni][rg];
            h1s[mi][ni] = h;
          }
      } else {
        // residual: h2 + h1
        #pragma unroll
        for (int mi = 0; mi < 4; ++mi)
          #pragma unroll
          for (int ni = 0; ni < 4; ++ni)
            #pragma unroll
            for (int rg = 0; rg < 4; ++rg)
              acc[mi][ni][rg] += (float)h1s[mi][ni][rg];
      }

      // prefetch next GEMM's chunk 0 into sB0 (last read of sB0 was c=14;
      // drained by the sPart __syncthreads below, read after 2 more barriers)
      stage_b(WT + ((size_t)(g + 1) << 18), sB0, wv, lane, 0);

      const float* gp = (g == 0) ? g2 : g3;
      const float* bp = (g == 0) ? b2 : b3;
      float gva[4], bva[4];
      #pragma unroll
      for (int ni = 0; ni < 4; ++ni) {
        int col = wv * 64 + ni * 16 + row16;
        gva[ni] = gp[col]; bva[ni] = bp[col];
      }

      // per-row LN stats: lane partial over ni, butterfly over row16 groups
      #pragma unroll
      for (int mi = 0; mi < 4; ++mi)
        #pragma unroll
        for (int rg = 0; rg < 4; ++rg) {
          float s = 0.f, q = 0.f;
          #pragma unroll
          for (int ni = 0; ni < 4; ++ni) {
            float v = acc[mi][ni][rg];
            s += v; q += v * v;
          }
          #pragma unroll
          for (int off = 1; off < 16; off <<= 1) {
            s += __shfl_xor(s, off, 16);
            q += __shfl_xor(q, off, 16);
          }
          if (row16 == 0)
            sPart[wv * 64 + mi * 16 + quad * 4 + rg] = make_float2(s, q);
        }
      __syncthreads();   // sPart ready; chunk-0 prefetch drained
      if (t < 64) {
        float s = 0.f, q = 0.f;
        #pragma unroll
        for (int w = 0; w < 8; ++w) {
          float2 p = sPart[w * 64 + t];
          s += p.x; q += p.y;
        }
        float mean = s * (1.f / 512.f);
        float var  = q * (1.f / 512.f) - mean * mean;
        sStat[t] = make_float2(mean, 1.f / sqrtf(var + 1e-5f));
      }
      __syncthreads();   // sStat ready

      // normalize -> write next A operand back into sX (in place, no global)
      #pragma unroll
      for (int mi = 0; mi < 4; ++mi)
        #pragma unroll
        for (int rg = 0; rg < 4; ++rg) {
          int row = mi * 16 + quad * 4 + rg;
          float2 st = sStat[row];
          #pragma unroll
          for (int ni = 0; ni < 4; ++ni) {
            int col = wv * 64 + ni * 16 + row16;
            sX[row * XS + col] = (f16)((acc[mi][ni][rg] - st.x) * st.y * gva[ni] + bva[ni]);
          }
        }
      __syncthreads();   // sX ready for next GEMM
    }
  }
}

// ---- Masked softmax over N: one block per (b, 64-o chunk), z staged in LDS ----
__global__ __launch_bounds__(256, 2) void softmax_kernel(const float* __restrict__ o3,
                                                         const int* __restrict__ mask,
                                                         float* __restrict__ out) {
  __shared__ float sz[NN * 64];
  __shared__ float sredm[4 * 64];
  __shared__ float sreds[4 * 64];
  __shared__ int   smask[NN];

  int b  = blockIdx.x >> 3;
  int oc = blockIdx.x & 7;
  int t  = threadIdx.x;
  int o_l = t & 63;
  int n_h = t >> 6;

  int mt = mask[b * NN + t];
  int any = __syncthreads_or(mt);
  smask[t] = (t == 0 && !any) ? 1 : mt;
  __syncthreads();

  const float* src = o3 + (((size_t)(b * NN)) << 9) + oc * 64;
  #pragma unroll 4
  for (int j = 0; j < 64; ++j) {
    int n = j * 4 + n_h;
    float v = src[((size_t)n << 9) + o_l];
    sz[n * 64 + o_l] = smask[n] ? v : -3.4e38f;
  }
  __syncthreads();

  float mx = -3.4e38f;
  #pragma unroll 8
  for (int i = 0; i < 64; ++i)
    mx = fmaxf(mx, sz[(n_h * 64 + i) * 64 + o_l]);
  sredm[n_h * 64 + o_l] = mx;
  __syncthreads();
  float m4 = fmaxf(fmaxf(sredm[o_l], sredm[64 + o_l]),
                   fmaxf(sredm[128 + o_l], sredm[192 + o_l]));

  float sm = 0.f;
  #pragma unroll 8
  for (int i = 0; i < 64; ++i)
    sm += __expf(sz[(n_h * 64 + i) * 64 + o_l] - m4);
  sreds[n_h * 64 + o_l] = sm;
  __syncthreads();
  float tot = sreds[o_l] + sreds[64 + o_l] + sreds[128 + o_l] + sreds[192 + o_l];
  float inv = 1.f / tot;

  float* dst = out + (((size_t)(b * NN)) << 9) + oc * 64;
  #pragma unroll 4
  for (int j = 0; j < 64; ++j) {
    int n = j * 4 + n_h;
    dst[((size_t)n << 9) + o_l] = __expf(sz[n * 64 + o_l] - m4) * inv;
  }
}

extern "C" void kernel_launch(void* const* d_in, const int* in_sizes, int n_in,
                              void* d_out, int out_size, void* d_ws, size_t ws_size,
                              hipStream_t stream) {
  const float* Obs = (const float*)d_in[0];
  const int*   msk = (const int*)d_in[1];
  const float* g1  = (const float*)d_in[2];
  const float* b1  = (const float*)d_in[3];
  const float* W1  = (const float*)d_in[4];
  const float* g2  = (const float*)d_in[5];
  const float* b2  = (const float*)d_in[6];
  const float* W2  = (const float*)d_in[7];
  const float* g3  = (const float*)d_in[8];
  const float* b3  = (const float*)d_in[9];
  const float* W3  = (const float*)d_in[10];
  float* out = (float*)d_out;

  char* ws = (char*)d_ws;
  const size_t MB = 1u << 20;
  float* Lg = (float*)ws;                  // [0, 64M) logits fp32
  f16*   WT = (f16*)(ws + 64 * MB);        // 1.5 MB

  prep_w_kernel<<<3072, 256, 0, stream>>>(W1, W2, W3, WT);
  mega_kernel<<<512, 512, 0, stream>>>(Obs, g1, b1, WT, g2, b2, g3, b3, Lg);
  softmax_kernel<<<1024, 256, 0, stream>>>(Lg, msk, out);
}

// Round 3
// 317.151 us; speedup vs baseline: 1.0261x; 1.0261x over previous
//
#include <hip/hip_runtime.h>

// B=128, N=256, D=O=512. R = B*N = 32768 rows.
// Pipeline (3 kernels):
//   prep_w:  W -> W^T f16
//   mega:    per 64-row slab: LN1(Obs)->sX, then {GEMM1+tanh -> h1(regs) ->
//            LN2 -> sX, GEMM2+tanh+h1 -> LN3 -> sX, GEMM3 -> logits fp32}.
//   softmax: masked softmax over N, register-resident (16 float4/thread)
// mega K-loop: NO barriers, NO LDS B-staging. Each wave reads only its own
// 64 B-rows, so bf fragments are loaded straight from global (L2-hot WT)
// into registers, double-buffered; the compiler's own register-dependency
// waitcnts are the only synchronization. sX (A operand) stays in LDS with
// XS=520 stride (2-way = free on ds_read_b128). Barriers exist only at the
// 3 phase boundaries (LN rewrites of sX) and in the logits epilogue.

#define NN 256

typedef _Float16 f16;
typedef __attribute__((ext_vector_type(4))) _Float16 f16x4;
typedef __attribute__((ext_vector_type(8))) _Float16 f16x8;
typedef __attribute__((ext_vector_type(4))) float f32x4;

#define XS    520   // sX row stride (f16): 1040 B -> row r starts bank 4r%32
#define EPS32 516   // f32 logits epilogue stride

__device__ __forceinline__ float fast_tanh(float x) {
  float e = __expf(2.f * x);
  return 1.f - 2.f * __builtin_amdgcn_rcpf(e + 1.f);
}

// ---- Transpose + f16-cast weights: W[d][o] fp32 -> WT[o][d] f16 (3 stages) ----
__global__ void prep_w_kernel(const float* __restrict__ W1, const float* __restrict__ W2,
                              const float* __restrict__ W3, f16* __restrict__ WT) {
  int idx = blockIdx.x * 256 + threadIdx.x;
  int s   = idx >> 18;
  int rem = idx & 0x3FFFF;
  int o   = rem >> 9;
  int d   = rem & 511;
  const float* W = (s == 0) ? W1 : (s == 1) ? W2 : W3;
  WT[idx] = (f16)W[d * 512 + o];
}

// one K-step: 4 ds_read_b128 of A fragments + 16 MFMA against preloaded bf
__device__ __forceinline__ void gemm_step(f32x4 acc[4][4], const f16* __restrict__ sXb,
                                          const f16x8 bf[4], int c) {
  f16x8 af[4];
  #pragma unroll
  for (int i = 0; i < 4; ++i)
    af[i] = *(const f16x8*)&sXb[i * 16 * XS + c * 32];
  #pragma unroll
  for (int mi = 0; mi < 4; ++mi)
    #pragma unroll
    for (int ni = 0; ni < 4; ++ni)
      acc[mi][ni] = __builtin_amdgcn_mfma_f32_16x16x32_f16(af[mi], bf[ni], acc[mi][ni], 0, 0, 0);
}

// ---- Mega kernel: LN1 + 3 GEMMs + 2 LNs + tanh + residual, one 64-row slab ----
__global__ __launch_bounds__(512, 2) void mega_kernel(
    const float* __restrict__ Obs,
    const float* __restrict__ g1, const float* __restrict__ b1,
    const f16* __restrict__ WT,
    const float* __restrict__ g2, const float* __restrict__ b2,
    const float* __restrict__ g3, const float* __restrict__ b3,
    float* __restrict__ outF) {
  __shared__ __align__(16) char smem[71168];
  f16* sX = (f16*)smem;                        // [64][XS] activations (A operand)
  float2* sPart = (float2*)(smem + 66560);     // [512] per-wave LN partials
  float2* sStat = (float2*)(smem + 70656);     // [64] (mean, inv) per row

  int t = threadIdx.x, lane = t & 63, wv = t >> 6;
  int row16 = lane & 15, quad = lane >> 4;
  int rBase = blockIdx.x * 64;

  // per-lane bases
  const f16* sXb = sX + row16 * XS + quad * 8;          // A fragment base
  const f16* bw  = WT + (((size_t)(wv * 64 + row16)) << 9) + quad * 8;  // B fragment base (g=0)

  f32x4 acc[4][4];
  f16x8 bfA[4], bfB[4];
  f16x4 h1s[4][4];   // residual tanh(A1@W1), register-resident across GEMM2

  // preload GEMM1 chunk 0 B-fragments (arrive during the LN1 prologue)
  #pragma unroll
  for (int i = 0; i < 4; ++i) bfA[i] = *(const f16x8*)(bw + i * 8192);

  // ---- LN1 prologue: each wave normalizes its 8 rows of Obs into sX ----
  {
    float4 w0 = *(const float4*)(g1 + lane * 4);
    float4 u0 = *(const float4*)(b1 + lane * 4);
    float4 w1 = *(const float4*)(g1 + 256 + lane * 4);
    float4 u1 = *(const float4*)(b1 + 256 + lane * 4);
    #pragma unroll
    for (int p = 0; p < 8; ++p) {
      int row = wv * 8 + p;
      const float* x = Obs + (((size_t)(rBase + row)) << 9);
      float4 v0 = *(const float4*)(x + lane * 4);
      float4 v1 = *(const float4*)(x + 256 + lane * 4);
      float s = v0.x + v0.y + v0.z + v0.w + v1.x + v1.y + v1.z + v1.w;
      float q = v0.x*v0.x + v0.y*v0.y + v0.z*v0.z + v0.w*v0.w
              + v1.x*v1.x + v1.y*v1.y + v1.z*v1.z + v1.w*v1.w;
      #pragma unroll
      for (int off = 1; off < 64; off <<= 1) {
        s += __shfl_xor(s, off, 64);
        q += __shfl_xor(q, off, 64);
      }
      float mean = s * (1.f / 512.f);
      float var  = q * (1.f / 512.f) - mean * mean;
      float inv  = 1.f / sqrtf(var + 1e-5f);
      f16x4 o0, o1;
      o0[0] = (f16)((v0.x - mean) * inv * w0.x + u0.x);
      o0[1] = (f16)((v0.y - mean) * inv * w0.y + u0.y);
      o0[2] = (f16)((v0.z - mean) * inv * w0.z + u0.z);
      o0[3] = (f16)((v0.w - mean) * inv * w0.w + u0.w);
      o1[0] = (f16)((v1.x - mean) * inv * w1.x + u1.x);
      o1[1] = (f16)((v1.y - mean) * inv * w1.y + u1.y);
      o1[2] = (f16)((v1.z - mean) * inv * w1.z + u1.z);
      o1[3] = (f16)((v1.w - mean) * inv * w1.w + u1.w);
      *(f16x4*)&sX[row * XS + lane * 4] = o0;
      *(f16x4*)&sX[row * XS + 256 + lane * 4] = o1;
    }
  }
  __syncthreads();   // sX (A1) ready for all waves

  for (int g = 0; g < 3; ++g) {
    #pragma unroll
    for (int mi = 0; mi < 4; ++mi)
      #pragma unroll
      for (int ni = 0; ni < 4; ++ni)
        acc[mi][ni] = (f32x4){0.f, 0.f, 0.f, 0.f};

    // K-loop: barrier-free, bf register-double-buffered (bfA preloaded c=0)
    #pragma unroll
    for (int c = 0; c < 16; c += 2) {
      #pragma unroll
      for (int i = 0; i < 4; ++i)
        bfB[i] = *(const f16x8*)(bw + i * 8192 + (c + 1) * 32);
      gemm_step(acc, sXb, bfA, c);
      if (c + 2 < 16) {
        #pragma unroll
        for (int i = 0; i < 4; ++i)
          bfA[i] = *(const f16x8*)(bw + i * 8192 + (c + 2) * 32);
      }
      gemm_step(acc, sXb, bfB, c + 1);
    }

    if (g == 2) {
      __syncthreads();   // all waves done reading sX -> safe to overlay sE
      float* sE = (float*)smem;
      #pragma unroll
      for (int half = 0; half < 2; ++half) {
        #pragma unroll
        for (int mi = 0; mi < 2; ++mi) {
          int rt = half * 2 + mi;
          #pragma unroll
          for (int ni = 0; ni < 4; ++ni) {
            int col = wv * 64 + ni * 16 + row16;
            #pragma unroll
            for (int rg = 0; rg < 4; ++rg)
              sE[(mi * 16 + quad * 4 + rg) * EPS32 + col] = acc[rt][ni][rg];
          }
        }
        __syncthreads();
        #pragma unroll
        for (int i = 0; i < 8; ++i) {
          int gi = t + i * 512;
          int row = gi >> 7, cg = (gi & 127) * 4;
          f32x4 v = *(const f32x4*)&sE[row * EPS32 + cg];
          *(f32x4*)&outF[(((size_t)(rBase + half * 32 + row)) << 9) + cg] = v;
        }
        __syncthreads();
      }
    } else {
      // tanh
      #pragma unroll
      for (int mi = 0; mi < 4; ++mi)
        #pragma unroll
        for (int ni = 0; ni < 4; ++ni)
          #pragma unroll
          for (int rg = 0; rg < 4; ++rg)
            acc[mi][ni][rg] = fast_tanh(acc[mi][ni][rg]);

      if (g == 0) {
        // stash h1 (same (row,col) mapping as GEMM2's acc)
        #pragma unroll
        for (int mi = 0; mi < 4; ++mi)
          #pragma unroll
          for (int ni = 0; ni < 4; ++ni) {
            f16x4 h;
            #pragma unroll
            for (int rg = 0; rg < 4; ++rg) h[rg] = (f16)acc[mi][ni][rg];
            h1s[mi][ni] = h;
          }
      } else {
        // residual: h2 + h1
        #pragma unroll
        for (int mi = 0; mi < 4; ++mi)
          #pragma unroll
          for (int ni = 0; ni < 4; ++ni)
            #pragma unroll
            for (int rg = 0; rg < 4; ++rg)
              acc[mi][ni][rg] += (float)h1s[mi][ni][rg];
      }

      const float* gp = (g == 0) ? g2 : g3;
      const float* bp = (g == 0) ? b2 : b3;
      float gva[4], bva[4];
      #pragma unroll
      for (int ni = 0; ni < 4; ++ni) {
        int col = wv * 64 + ni * 16 + row16;
        gva[ni] = gp[col]; bva[ni] = bp[col];
      }

      // per-row LN stats: lane partial over ni, butterfly over 16-lane groups
      #pragma unroll
      for (int mi = 0; mi < 4; ++mi)
        #pragma unroll
        for (int rg = 0; rg < 4; ++rg) {
          float s = 0.f, q = 0.f;
          #pragma unroll
          for (int ni = 0; ni < 4; ++ni) {
            float v = acc[mi][ni][rg];
            s += v; q += v * v;
          }
          #pragma unroll
          for (int off = 1; off < 16; off <<= 1) {
            s += __shfl_xor(s, off, 16);
            q += __shfl_xor(q, off, 16);
          }
          if (row16 == 0)
            sPart[wv * 64 + mi * 16 + quad * 4 + rg] = make_float2(s, q);
        }
      __syncthreads();   // sPart ready; also: all waves done reading sX
      if (t < 64) {
        float s = 0.f, q = 0.f;
        #pragma unroll
        for (int w = 0; w < 8; ++w) {
          float2 p = sPart[w * 64 + t];
          s += p.x; q += p.y;
        }
        float mean = s * (1.f / 512.f);
        float var  = q * (1.f / 512.f) - mean * mean;
        sStat[t] = make_float2(mean, 1.f / sqrtf(var + 1e-5f));
      }

      // preload next GEMM's chunk-0 B-fragments (covers L2 latency under LN)
      bw += 262144;
      #pragma unroll
      for (int i = 0; i < 4; ++i) bfA[i] = *(const f16x8*)(bw + i * 8192);

      __syncthreads();   // sStat ready

      // normalize -> write next A operand back into sX (in place)
      #pragma unroll
      for (int mi = 0; mi < 4; ++mi)
        #pragma unroll
        for (int rg = 0; rg < 4; ++rg) {
          int row = mi * 16 + quad * 4 + rg;
          float2 st = sStat[row];
          #pragma unroll
          for (int ni = 0; ni < 4; ++ni) {
            int col = wv * 64 + ni * 16 + row16;
            sX[row * XS + col] = (f16)((acc[mi][ni][rg] - st.x) * st.y * gva[ni] + bva[ni]);
          }
        }
      __syncthreads();   // sX ready for next GEMM
    }
  }
}

// ---- Masked softmax over N: register-resident. Block = (b, 64-o chunk). ----
// Thread (c4 = t&15, nh = t>>4) owns cols oc*64 + c4*4..+3, rows n = nh+16j.
__global__ __launch_bounds__(256, 2) void softmax_kernel(const float* __restrict__ o3,
                                                         const int* __restrict__ mask,
                                                         float* __restrict__ out) {
  __shared__ float4 smx[16][16];   // [nh][c4] partial col-maxes
  __shared__ float4 sms[16][16];   // [nh][c4] partial col-sums
  __shared__ int    smask[NN];

  int b  = blockIdx.x >> 3;
  int oc = blockIdx.x & 7;
  int t  = threadIdx.x;
  int c4 = t & 15;
  int nh = t >> 4;

  const float4* src = (const float4*)(o3 + (((size_t)(b * NN)) << 9)) + oc * 16 + c4;
  float4 v[16];
  #pragma unroll
  for (int j = 0; j < 16; ++j)
    v[j] = src[(size_t)(nh + 16 * j) * 128];

  int mt = mask[b * NN + t];
  int any = __syncthreads_or(mt);
  smask[t] = (t == 0 && !any) ? 1 : mt;
  __syncthreads();

  const float NEG = -3.4e38f;
  #pragma unroll
  for (int j = 0; j < 16; ++j)
    if (!smask[nh + 16 * j]) v[j] = (float4){NEG, NEG, NEG, NEG};

  // col max over this thread's 16 rows, then over the 16 nh groups via LDS
  float4 m4 = v[0];
  #pragma unroll
  for (int j = 1; j < 16; ++j) {
    m4.x = fmaxf(m4.x, v[j].x); m4.y = fmaxf(m4.y, v[j].y);
    m4.z = fmaxf(m4.z, v[j].z); m4.w = fmaxf(m4.w, v[j].w);
  }
  smx[nh][c4] = m4;
  __syncthreads();
  float4 mm = smx[0][c4];
  #pragma unroll
  for (int k = 1; k < 16; ++k) {
    float4 o = smx[k][c4];
    mm.x = fmaxf(mm.x, o.x); mm.y = fmaxf(mm.y, o.y);
    mm.z = fmaxf(mm.z, o.z); mm.w = fmaxf(mm.w, o.w);
  }

  // col sum of exp
  float4 s4 = {0.f, 0.f, 0.f, 0.f};
  #pragma unroll
  for (int j = 0; j < 16; ++j) {
    s4.x += __expf(v[j].x - mm.x); s4.y += __expf(v[j].y - mm.y);
    s4.z += __expf(v[j].z - mm.z); s4.w += __expf(v[j].w - mm.w);
  }
  sms[nh][c4] = s4;
  __syncthreads();
  float4 tot = sms[0][c4];
  #pragma unroll
  for (int k = 1; k < 16; ++k) {
    float4 o = sms[k][c4];
    tot.x += o.x; tot.y += o.y; tot.z += o.z; tot.w += o.w;
  }
  float4 inv = {1.f / tot.x, 1.f / tot.y, 1.f / tot.z, 1.f / tot.w};

  float4* dst = (float4*)(out + (((size_t)(b * NN)) << 9)) + oc * 16 + c4;
  #pragma unroll
  for (int j = 0; j < 16; ++j) {
    float4 r;
    r.x = __expf(v[j].x - mm.x) * inv.x;
    r.y = __expf(v[j].y - mm.y) * inv.y;
    r.z = __expf(v[j].z - mm.z) * inv.z;
    r.w = __expf(v[j].w - mm.w) * inv.w;
    dst[(size_t)(nh + 16 * j) * 128] = r;
  }
}

extern "C" void kernel_launch(void* const* d_in, const int* in_sizes, int n_in,
                              void* d_out, int out_size, void* d_ws, size_t ws_size,
                              hipStream_t stream) {
  const float* Obs = (const float*)d_in[0];
  const int*   msk = (const int*)d_in[1];
  const float* g1  = (const float*)d_in[2];
  const float* b1  = (const float*)d_in[3];
  const float* W1  = (const float*)d_in[4];
  const float* g2  = (const float*)d_in[5];
  const float* b2  = (const float*)d_in[6];
  const float* W2  = (const float*)d_in[7];
  const float* g3  = (const float*)d_in[8];
  const float* b3  = (const float*)d_in[9];
  const float* W3  = (const float*)d_in[10];
  float* out = (float*)d_out;

  char* ws = (char*)d_ws;
  const size_t MB = 1u << 20;
  float* Lg = (float*)ws;                  // [0, 64M) logits fp32
  f16*   WT = (f16*)(ws + 64 * MB);        // 1.5 MB

  prep_w_kernel<<<3072, 256, 0, stream>>>(W1, W2, W3, WT);
  mega_kernel<<<512, 512, 0, stream>>>(Obs, g1, b1, WT, g2, b2, g3, b3, Lg);
  softmax_kernel<<<1024, 256, 0, stream>>>(Lg, msk, out);
}

// Round 4
// 278.922 us; speedup vs baseline: 1.1667x; 1.1371x over previous
//
#include <hip/hip_runtime.h>

// B=128, N=256, D=O=512. R = B*N = 32768 rows.
// Pipeline (3 kernels):
//   prep_w:  W -> chunk-tiled W^T f16: WTc[g][c][r][32], c = K-chunk of 32.
//   mega:    per 64-row slab: LN1(Obs)->sX, then {GEMM1+tanh -> h1(regs) ->
//            LN2 -> sX, GEMM2+tanh+h1 -> LN3 -> sX, GEMM3 -> logits fp32}.
//   softmax: masked softmax over N, register-resident (16 float4/thread)
// mega K-loop: barrier-free; B fragments loaded straight from global with the
// chunk-tiled layout so each wave-instruction covers ONE contiguous 1 KB
// segment (round-3's row-major layout scattered each load over 16 lines 1 KB
// apart -> VMEM-issue/L2-request bound, MfmaUtil 9.4%). A stays in LDS
// (XS=520: ds_read_b128 slot = (row16+quad)%8, uniform -> conflict-free).

#define NN 256

typedef _Float16 f16;
typedef __attribute__((ext_vector_type(4))) _Float16 f16x4;
typedef __attribute__((ext_vector_type(8))) _Float16 f16x8;
typedef __attribute__((ext_vector_type(4))) float f32x4;

#define XS    520   // sX row stride (f16)
#define EPS32 516   // f32 logits epilogue stride

__device__ __forceinline__ float fast_tanh(float x) {
  float e = __expf(2.f * x);
  return 1.f - 2.f * __builtin_amdgcn_rcpf(e + 1.f);
}

// ---- W[d][o] fp32 -> WTc[g][c][o][dlow] f16 (chunk-tiled transpose) ----
__global__ void prep_w_kernel(const float* __restrict__ W1, const float* __restrict__ W2,
                              const float* __restrict__ W3, f16* __restrict__ WTc) {
  int idx = blockIdx.x * 256 + threadIdx.x;
  int g    = idx >> 18;
  int rem  = idx & 0x3FFFF;
  int c    = rem >> 14;          // K-chunk (16 of them)
  int o    = (rem >> 5) & 511;   // output col
  int dlow = rem & 31;           // k within chunk
  const float* W = (g == 0) ? W1 : (g == 1) ? W2 : W3;
  WTc[idx] = (f16)W[(c * 32 + dlow) * 512 + o];
}

// one K-step: 4 ds_read_b128 of A fragments + 16 MFMA against preloaded bf
__device__ __forceinline__ void gemm_step(f32x4 acc[4][4], const f16* __restrict__ sXb,
                                          const f16x8 bf[4], int c) {
  f16x8 af[4];
  #pragma unroll
  for (int i = 0; i < 4; ++i)
    af[i] = *(const f16x8*)&sXb[i * 16 * XS + c * 32];
  #pragma unroll
  for (int mi = 0; mi < 4; ++mi)
    #pragma unroll
    for (int ni = 0; ni < 4; ++ni)
      acc[mi][ni] = __builtin_amdgcn_mfma_f32_16x16x32_f16(af[mi], bf[ni], acc[mi][ni], 0, 0, 0);
}

// ---- Mega kernel: LN1 + 3 GEMMs + 2 LNs + tanh + residual, one 64-row slab ----
__global__ __launch_bounds__(512, 2) void mega_kernel(
    const float* __restrict__ Obs,
    const float* __restrict__ g1, const float* __restrict__ b1,
    const f16* __restrict__ WTc,
    const float* __restrict__ g2, const float* __restrict__ b2,
    const float* __restrict__ g3, const float* __restrict__ b3,
    float* __restrict__ outF) {
  __shared__ __align__(16) char smem[71168];
  f16* sX = (f16*)smem;                        // [64][XS] activations (A operand)
  float2* sPart = (float2*)(smem + 66560);     // [512] per-wave LN partials
  float2* sStat = (float2*)(smem + 70656);     // [64] (mean, inv) per row

  int t = threadIdx.x, lane = t & 63, wv = t >> 6;
  int row16 = lane & 15, quad = lane >> 4;
  int rBase = blockIdx.x * 64;

  // per-lane bases
  const f16* sXb = sX + row16 * XS + quad * 8;                 // A fragment base
  // B fragment base (g=0): chunk-tiled. Wave's rows wv*64.., lane covers
  // row16*64B + quad*16B of the contiguous [16 rows][32 f16] = 1 KB segment.
  const f16* bw = WTc + wv * 2048 + row16 * 32 + quad * 8;

  f32x4 acc[4][4];
  f16x8 bfA[4], bfB[4];
  f16x4 h1s[4][4];   // residual tanh(A1@W1), register-resident across GEMM2

  // preload GEMM1 chunk 0 B-fragments (arrive during the LN1 prologue)
  #pragma unroll
  for (int i = 0; i < 4; ++i) bfA[i] = *(const f16x8*)(bw + i * 512);

  // ---- LN1 prologue: each wave normalizes its 8 rows of Obs into sX ----
  {
    float4 w0 = *(const float4*)(g1 + lane * 4);
    float4 u0 = *(const float4*)(b1 + lane * 4);
    float4 w1 = *(const float4*)(g1 + 256 + lane * 4);
    float4 u1 = *(const float4*)(b1 + 256 + lane * 4);
    #pragma unroll
    for (int p = 0; p < 8; ++p) {
      int row = wv * 8 + p;
      const float* x = Obs + (((size_t)(rBase + row)) << 9);
      float4 v0 = *(const float4*)(x + lane * 4);
      float4 v1 = *(const float4*)(x + 256 + lane * 4);
      float s = v0.x + v0.y + v0.z + v0.w + v1.x + v1.y + v1.z + v1.w;
      float q = v0.x*v0.x + v0.y*v0.y + v0.z*v0.z + v0.w*v0.w
              + v1.x*v1.x + v1.y*v1.y + v1.z*v1.z + v1.w*v1.w;
      #pragma unroll
      for (int off = 1; off < 64; off <<= 1) {
        s += __shfl_xor(s, off, 64);
        q += __shfl_xor(q, off, 64);
      }
      float mean = s * (1.f / 512.f);
      float var  = q * (1.f / 512.f) - mean * mean;
      float inv  = 1.f / sqrtf(var + 1e-5f);
      f16x4 o0, o1;
      o0[0] = (f16)((v0.x - mean) * inv * w0.x + u0.x);
      o0[1] = (f16)((v0.y - mean) * inv * w0.y + u0.y);
      o0[2] = (f16)((v0.z - mean) * inv * w0.z + u0.z);
      o0[3] = (f16)((v0.w - mean) * inv * w0.w + u0.w);
      o1[0] = (f16)((v1.x - mean) * inv * w1.x + u1.x);
      o1[1] = (f16)((v1.y - mean) * inv * w1.y + u1.y);
      o1[2] = (f16)((v1.z - mean) * inv * w1.z + u1.z);
      o1[3] = (f16)((v1.w - mean) * inv * w1.w + u1.w);
      *(f16x4*)&sX[row * XS + lane * 4] = o0;
      *(f16x4*)&sX[row * XS + 256 + lane * 4] = o1;
    }
  }
  __syncthreads();   // sX (A1) ready for all waves

  for (int g = 0; g < 3; ++g) {
    #pragma unroll
    for (int mi = 0; mi < 4; ++mi)
      #pragma unroll
      for (int ni = 0; ni < 4; ++ni)
        acc[mi][ni] = (f32x4){0.f, 0.f, 0.f, 0.f};

    // K-loop: barrier-free, bf register-double-buffered (bfA preloaded c=0).
    // chunk c's 32-f16 K-slice of this wave's 64 B-rows is at bw + c*16384.
    #pragma unroll
    for (int c = 0; c < 16; c += 2) {
      #pragma unroll
      for (int i = 0; i < 4; ++i)
        bfB[i] = *(const f16x8*)(bw + (c + 1) * 16384 + i * 512);
      gemm_step(acc, sXb, bfA, c);
      if (c + 2 < 16) {
        #pragma unroll
        for (int i = 0; i < 4; ++i)
          bfA[i] = *(const f16x8*)(bw + (c + 2) * 16384 + i * 512);
      }
      gemm_step(acc, sXb, bfB, c + 1);
    }

    if (g == 2) {
      __syncthreads();   // all waves done reading sX -> safe to overlay sE
      float* sE = (float*)smem;
      #pragma unroll
      for (int half = 0; half < 2; ++half) {
        #pragma unroll
        for (int mi = 0; mi < 2; ++mi) {
          int rt = half * 2 + mi;
          #pragma unroll
          for (int ni = 0; ni < 4; ++ni) {
            int col = wv * 64 + ni * 16 + row16;
            #pragma unroll
            for (int rg = 0; rg < 4; ++rg)
              sE[(mi * 16 + quad * 4 + rg) * EPS32 + col] = acc[rt][ni][rg];
          }
        }
        __syncthreads();
        #pragma unroll
        for (int i = 0; i < 8; ++i) {
          int gi = t + i * 512;
          int row = gi >> 7, cg = (gi & 127) * 4;
          f32x4 v = *(const f32x4*)&sE[row * EPS32 + cg];
          *(f32x4*)&outF[(((size_t)(rBase + half * 32 + row)) << 9) + cg] = v;
        }
        __syncthreads();
      }
    } else {
      // tanh
      #pragma unroll
      for (int mi = 0; mi < 4; ++mi)
        #pragma unroll
        for (int ni = 0; ni < 4; ++ni)
          #pragma unroll
          for (int rg = 0; rg < 4; ++rg)
            acc[mi][ni][rg] = fast_tanh(acc[mi][ni][rg]);

      if (g == 0) {
        // stash h1 (same (row,col) mapping as GEMM2's acc)
        #pragma unroll
        for (int mi = 0; mi < 4; ++mi)
          #pragma unroll
          for (int ni = 0; ni < 4; ++ni) {
            f16x4 h;
            #pragma unroll
            for (int rg = 0; rg < 4; ++rg) h[rg] = (f16)acc[mi][ni][rg];
            h1s[mi][ni] = h;
          }
      } else {
        // residual: h2 + h1
        #pragma unroll
        for (int mi = 0; mi < 4; ++mi)
          #pragma unroll
          for (int ni = 0; ni < 4; ++ni)
            #pragma unroll
            for (int rg = 0; rg < 4; ++rg)
              acc[mi][ni][rg] += (float)h1s[mi][ni][rg];
      }

      const float* gp = (g == 0) ? g2 : g3;
      const float* bp = (g == 0) ? b2 : b3;
      float gva[4], bva[4];
      #pragma unroll
      for (int ni = 0; ni < 4; ++ni) {
        int col = wv * 64 + ni * 16 + row16;
        gva[ni] = gp[col]; bva[ni] = bp[col];
      }

      // per-row LN stats: lane partial over ni, butterfly over 16-lane groups
      #pragma unroll
      for (int mi = 0; mi < 4; ++mi)
        #pragma unroll
        for (int rg = 0; rg < 4; ++rg) {
          float s = 0.f, q = 0.f;
          #pragma unroll
          for (int ni = 0; ni < 4; ++ni) {
            float v = acc[mi][ni][rg];
            s += v; q += v * v;
          }
          #pragma unroll
          for (int off = 1; off < 16; off <<= 1) {
            s += __shfl_xor(s, off, 16);
            q += __shfl_xor(q, off, 16);
          }
          if (row16 == 0)
            sPart[wv * 64 + mi * 16 + quad * 4 + rg] = make_float2(s, q);
        }
      __syncthreads();   // sPart ready; also: all waves done reading sX
      if (t < 64) {
        float s = 0.f, q = 0.f;
        #pragma unroll
        for (int w = 0; w < 8; ++w) {
          float2 p = sPart[w * 64 + t];
          s += p.x; q += p.y;
        }
        float mean = s * (1.f / 512.f);
        float var  = q * (1.f / 512.f) - mean * mean;
        sStat[t] = make_float2(mean, 1.f / sqrtf(var + 1e-5f));
      }

      // preload next GEMM's chunk-0 B-fragments (covers L2 latency under LN)
      bw += 262144;
      #pragma unroll
      for (int i = 0; i < 4; ++i) bfA[i] = *(const f16x8*)(bw + i * 512);

      __syncthreads();   // sStat ready

      // normalize -> write next A operand back into sX (in place)
      #pragma unroll
      for (int mi = 0; mi < 4; ++mi)
        #pragma unroll
        for (int rg = 0; rg < 4; ++rg) {
          int row = mi * 16 + quad * 4 + rg;
          float2 st = sStat[row];
          #pragma unroll
          for (int ni = 0; ni < 4; ++ni) {
            int col = wv * 64 + ni * 16 + row16;
            sX[row * XS + col] = (f16)((acc[mi][ni][rg] - st.x) * st.y * gva[ni] + bva[ni]);
          }
        }
      __syncthreads();   // sX ready for next GEMM
    }
  }
}

// ---- Masked softmax over N: register-resident. Block = (b, 64-o chunk). ----
// Thread (c4 = t&15, nh = t>>4) owns cols oc*64 + c4*4..+3, rows n = nh+16j.
__global__ __launch_bounds__(256, 2) void softmax_kernel(const float* __restrict__ o3,
                                                         const int* __restrict__ mask,
                                                         float* __restrict__ out) {
  __shared__ float4 smx[16][16];   // [nh][c4] partial col-maxes
  __shared__ float4 sms[16][16];   // [nh][c4] partial col-sums
  __shared__ int    smask[NN];

  int b  = blockIdx.x >> 3;
  int oc = blockIdx.x & 7;
  int t  = threadIdx.x;
  int c4 = t & 15;
  int nh = t >> 4;

  const float4* src = (const float4*)(o3 + (((size_t)(b * NN)) << 9)) + oc * 16 + c4;
  float4 v[16];
  #pragma unroll
  for (int j = 0; j < 16; ++j)
    v[j] = src[(size_t)(nh + 16 * j) * 128];

  int mt = mask[b * NN + t];
  int any = __syncthreads_or(mt);
  smask[t] = (t == 0 && !any) ? 1 : mt;
  __syncthreads();

  const float NEG = -3.4e38f;
  #pragma unroll
  for (int j = 0; j < 16; ++j)
    if (!smask[nh + 16 * j]) v[j] = (float4){NEG, NEG, NEG, NEG};

  // col max over this thread's 16 rows, then over the 16 nh groups via LDS
  float4 m4 = v[0];
  #pragma unroll
  for (int j = 1; j < 16; ++j) {
    m4.x = fmaxf(m4.x, v[j].x); m4.y = fmaxf(m4.y, v[j].y);
    m4.z = fmaxf(m4.z, v[j].z); m4.w = fmaxf(m4.w, v[j].w);
  }
  smx[nh][c4] = m4;
  __syncthreads();
  float4 mm = smx[0][c4];
  #pragma unroll
  for (int k = 1; k < 16; ++k) {
    float4 o = smx[k][c4];
    mm.x = fmaxf(mm.x, o.x); mm.y = fmaxf(mm.y, o.y);
    mm.z = fmaxf(mm.z, o.z); mm.w = fmaxf(mm.w, o.w);
  }

  // col sum of exp
  float4 s4 = {0.f, 0.f, 0.f, 0.f};
  #pragma unroll
  for (int j = 0; j < 16; ++j) {
    s4.x += __expf(v[j].x - mm.x); s4.y += __expf(v[j].y - mm.y);
    s4.z += __expf(v[j].z - mm.z); s4.w += __expf(v[j].w - mm.w);
  }
  sms[nh][c4] = s4;
  __syncthreads();
  float4 tot = sms[0][c4];
  #pragma unroll
  for (int k = 1; k < 16; ++k) {
    float4 o = sms[k][c4];
    tot.x += o.x; tot.y += o.y; tot.z += o.z; tot.w += o.w;
  }
  float4 inv = {1.f / tot.x, 1.f / tot.y, 1.f / tot.z, 1.f / tot.w};

  float4* dst = (float4*)(out + (((size_t)(b * NN)) << 9)) + oc * 16 + c4;
  #pragma unroll
  for (int j = 0; j < 16; ++j) {
    float4 r;
    r.x = __expf(v[j].x - mm.x) * inv.x;
    r.y = __expf(v[j].y - mm.y) * inv.y;
    r.z = __expf(v[j].z - mm.z) * inv.z;
    r.w = __expf(v[j].w - mm.w) * inv.w;
    dst[(size_t)(nh + 16 * j) * 128] = r;
  }
}

extern "C" void kernel_launch(void* const* d_in, const int* in_sizes, int n_in,
                              void* d_out, int out_size, void* d_ws, size_t ws_size,
                              hipStream_t stream) {
  const float* Obs = (const float*)d_in[0];
  const int*   msk = (const int*)d_in[1];
  const float* g1  = (const float*)d_in[2];
  const float* b1  = (const float*)d_in[3];
  const float* W1  = (const float*)d_in[4];
  const float* g2  = (const float*)d_in[5];
  const float* b2  = (const float*)d_in[6];
  const float* W2  = (const float*)d_in[7];
  const float* g3  = (const float*)d_in[8];
  const float* b3  = (const float*)d_in[9];
  const float* W3  = (const float*)d_in[10];
  float* out = (float*)d_out;

  char* ws = (char*)d_ws;
  const size_t MB = 1u << 20;
  float* Lg = (float*)ws;                  // [0, 64M) logits fp32
  f16*   WTc = (f16*)(ws + 64 * MB);       // 1.5 MB chunk-tiled

  prep_w_kernel<<<3072, 256, 0, stream>>>(W1, W2, W3, WTc);
  mega_kernel<<<512, 512, 0, stream>>>(Obs, g1, b1, WTc, g2, b2, g3, b3, Lg);
  softmax_kernel<<<1024, 256, 0, stream>>>(Lg, msk, out);
}